// Round 10
// baseline (1118.243 us; speedup 1.0000x reference)
//
#include <hip/hip_runtime.h>
#include <cmath>

#define BSZ 4
#define TLEN 196
#define SLEN 392
#define DMODEL 1024
#define DINNER 2048
#define DSTATE 16
#define DTRANK 64

typedef unsigned short u16;

static __device__ __forceinline__ float b2f(u16 u){
  union { unsigned int i; float f; } v; v.i = ((unsigned int)u) << 16; return v.f;
}
static __device__ __forceinline__ u16 f2b(float f){
  unsigned int x = __float_as_uint(f);
  unsigned int r = (x + 0x7fffu + ((x >> 16) & 1u)) >> 16;
  return (u16)r;
}
static __device__ __forceinline__ float siluf(float x){ return x / (1.f + expf(-x)); }
static __device__ __forceinline__ float softplusf(float x){
  return (x > 20.f) ? x : log1pf(expf(x));
}

__global__ void zero_out_k(float* __restrict__ out, int n){
  int i = blockIdx.x*256 + threadIdx.x;
  if (i < n) out[i] = 0.f;
}

// ---------------- 1. timestep embedding (int32 ts, verified) ----------------
__global__ __launch_bounds__(256) void temb_k(const int* __restrict__ ts, float* __restrict__ temb){
  int i = blockIdx.x*256 + threadIdx.x;           // 2048
  if (i >= BSZ*512) return;
  int b = i >> 9, k = i & 511;
  float fr = expf(-9.210340371976184f * (float)k / 512.0f);
  float arg = (float)ts[b] * fr;
  temb[b*1024 + k]       = cosf(arg);
  temb[b*1024 + 512 + k] = sinf(arg);
}

// ---------------- 2. small time-MLP layer (4 rows) ----------------
__global__ __launch_bounds__(256) void mlp_k(const float* __restrict__ src, const float* __restrict__ W,
                                             const float* __restrict__ bias, float* __restrict__ dst,
                                             int K, int N, int act){
  __shared__ float s[4*2048];
  __shared__ float4 red[256];
  int tid = threadIdx.x; int e = blockIdx.x;
  for (int i = tid; i < 4*K; i += 256) s[i] = src[i];
  __syncthreads();
  float a0=0,a1=0,a2=0,a3=0;
  for (int d = tid; d < K; d += 256){
    float w = W[(size_t)e*K + d];
    a0 += w*s[d]; a1 += w*s[K+d]; a2 += w*s[2*K+d]; a3 += w*s[3*K+d];
  }
  red[tid] = make_float4(a0,a1,a2,a3);
  __syncthreads();
  for (int st = 128; st > 0; st >>= 1){
    if (tid < st){
      float4 o = red[tid+st]; float4 m = red[tid];
      m.x+=o.x; m.y+=o.y; m.z+=o.z; m.w+=o.w; red[tid]=m;
    }
    __syncthreads();
  }
  if (tid == 0){
    float bs = bias[e];
    float4 v = red[0];
    float vv[4] = {v.x, v.y, v.z, v.w};
    for (int b = 0; b < 4; b++){
      float x = vv[b] + bs;
      if (act) x = siluf(x);
      dst[b*N + e] = x;
    }
  }
}

// ---------------- 3. build seq (LN -> bf16) + rms rstd ----------------
__global__ __launch_bounds__(256) void build_seq_k(const float* __restrict__ x_r, const float* __restrict__ motion,
                                                   const float* __restrict__ pos, const float* __restrict__ embt,
                                                   const float* __restrict__ g, const float* __restrict__ bb,
                                                   u16* __restrict__ seqb, float* __restrict__ rstd){
  __shared__ float r1[256], r2[256];
  int r = blockIdx.x; int b = r / SLEN; int l = r % SLEN;
  int tid = threadIdx.x;
  float v[4]; float s = 0.f, s2 = 0.f;
  int lp = (l < TLEN) ? l : l - TLEN;
  for (int i = 0; i < 4; i++){
    int d = tid + i*256;
    float val = pos[(size_t)lp*DMODEL + d];
    if (l < TLEN) val += motion[((size_t)b*TLEN + l)*DMODEL + d];
    else          val += x_r[((size_t)b*TLEN + (l-TLEN))*DMODEL + d] + embt[(size_t)b*DMODEL + d];
    v[i] = val; s += val; s2 += val*val;
  }
  r1[tid] = s; r2[tid] = s2; __syncthreads();
  for (int st = 128; st > 0; st >>= 1){
    if (tid < st){ r1[tid]+=r1[tid+st]; r2[tid]+=r2[tid+st]; }
    __syncthreads();
  }
  float mu = r1[0]/1024.f;
  float var = r2[0]/1024.f - mu*mu;
  float rs = rsqrtf(var + 1e-5f);
  __syncthreads();
  float q = 0.f;
  for (int i = 0; i < 4; i++){
    int d = tid + i*256;
    float yv = (v[i]-mu)*rs*g[d] + bb[d];
    seqb[(size_t)r*DMODEL + d] = f2b(yv);
    q += yv*yv;
  }
  r1[tid] = q; __syncthreads();
  for (int st = 128; st > 0; st >>= 1){
    if (tid < st) r1[tid]+=r1[tid+st];
    __syncthreads();
  }
  if (tid == 0) rstd[r] = rsqrtf(r1[0]/1024.f + 1e-5f);
}

// ---------------- tiled GEMM: C[M,N] = A[M,K] * W[N,K]^T  (W f32) ----------------
// MODE 0: in_proj (A bf16 scaled rowScale*colScale; col<2048 -> Cu bf16, col>=2048 -> Z2 for l>=196)
// MODE 1: x_proj (A bf16 -> C f32)
// MODE 2: dt_proj (A f32 -> softplus(+bias) -> C bf16)
// MODE 3: out_proj (A bf16 row-remap -> C f32)
template<int MODE, int AF, int CF>
__global__ __launch_bounds__(256) void gemm_k(const void* __restrict__ Ap, int lda, int M, int K,
                                              const float* __restrict__ W, int N,
                                              void* __restrict__ Cp, int ldc,
                                              const float* __restrict__ rowScale,
                                              const float* __restrict__ colScale,
                                              const float* __restrict__ bias,
                                              u16* __restrict__ Z2){
  __shared__ float As[16][68];
  __shared__ float Ws[16][68];
  const float* Af = (const float*)Ap;
  const u16*   Au = (const u16*)Ap;
  float* Cf = (float*)Cp;
  u16*   Cu = (u16*)Cp;
  int tid = threadIdx.x;
  int ntile = blockIdx.x, mtile = blockIdx.y;
  int m_l = tid >> 2, kq = (tid & 3) << 2;
  float acc[4][4] = {};
  int m0 = (tid & 15) << 2;
  int n0 = (tid >> 4) << 2;

  for (int k0 = 0; k0 < K; k0 += 16){
    int row = mtile*64 + m_l;
    float4 av = make_float4(0.f,0.f,0.f,0.f);
    if (row < M){
      size_t rr = row;
      if (MODE == 3) rr = row + 196*(row/196 + 1);
      if (AF == 0){
        av = *(const float4*)(Af + rr*(size_t)lda + k0 + kq);
      } else {
        ushort4 u = *(const ushort4*)(Au + rr*(size_t)lda + k0 + kq);
        av.x=b2f(u.x); av.y=b2f(u.y); av.z=b2f(u.z); av.w=b2f(u.w);
      }
      if (MODE == 0){
        float rsv = rowScale[row];
        av.x *= rsv * colScale[k0+kq+0];
        av.y *= rsv * colScale[k0+kq+1];
        av.z *= rsv * colScale[k0+kq+2];
        av.w *= rsv * colScale[k0+kq+3];
      }
    }
    As[kq+0][m_l]=av.x; As[kq+1][m_l]=av.y; As[kq+2][m_l]=av.z; As[kq+3][m_l]=av.w;

    int n = ntile*64 + m_l;
    float4 wv = make_float4(0.f,0.f,0.f,0.f);
    if (n < N) wv = *(const float4*)(W + (size_t)n*K + k0 + kq);
    Ws[kq+0][m_l]=wv.x; Ws[kq+1][m_l]=wv.y; Ws[kq+2][m_l]=wv.z; Ws[kq+3][m_l]=wv.w;
    __syncthreads();

    #pragma unroll
    for (int k = 0; k < 16; k++){
      float4 a = *(const float4*)&As[k][m0];
      float4 b = *(const float4*)&Ws[k][n0];
      acc[0][0]+=a.x*b.x; acc[0][1]+=a.x*b.y; acc[0][2]+=a.x*b.z; acc[0][3]+=a.x*b.w;
      acc[1][0]+=a.y*b.x; acc[1][1]+=a.y*b.y; acc[1][2]+=a.y*b.z; acc[1][3]+=a.y*b.w;
      acc[2][0]+=a.z*b.x; acc[2][1]+=a.z*b.y; acc[2][2]+=a.z*b.z; acc[2][3]+=a.z*b.w;
      acc[3][0]+=a.w*b.x; acc[3][1]+=a.w*b.y; acc[3][2]+=a.w*b.z; acc[3][3]+=a.w*b.w;
    }
    __syncthreads();
  }

  #pragma unroll
  for (int i = 0; i < 4; i++){
    int row = mtile*64 + (tid & 15)*4 + i;
    if (row >= M) continue;
    #pragma unroll
    for (int j = 0; j < 4; j++){
      int col = ntile*64 + (tid >> 4)*4 + j;
      if (col >= N) continue;
      float val = acc[i][j];
      if (MODE == 0){
        if (col < DINNER){
          Cu[(size_t)row*DINNER + col] = f2b(val);
        } else {
          int l = row % SLEN;
          if (l >= TLEN){
            int b = row / SLEN;
            Z2[((size_t)(b*TLEN + (l - TLEN)))*DINNER + (col - DINNER)] = f2b(val);
          }
        }
      } else {
        if (MODE == 2) val = softplusf(val + bias[col]);
        if (CF == 0) Cf[(size_t)row*ldc + col] = val;
        else         Cu[(size_t)row*ldc + col] = f2b(val);
      }
    }
  }
}

// ---------------- depthwise causal conv(4) + bias + silu ----------------
__global__ __launch_bounds__(256) void conv_k(const u16* __restrict__ xpre, const float* __restrict__ cw,
                                              const float* __restrict__ cb, u16* __restrict__ xc){
  int idx = blockIdx.x*256 + threadIdx.x;
  int e = idx & (DINNER-1);
  int l = (idx >> 11) % SLEN;
  int b = idx / (SLEN*DINNER);
  float a = cb[e];
  #pragma unroll
  for (int k = 0; k < 4; k++){
    int li = l - 3 + k;
    if (li >= 0) a += cw[e*4 + k] * b2f(xpre[((size_t)(b*SLEN + li))*DINNER + e]);
  }
  xc[((size_t)(b*SLEN + l))*DINNER + e] = f2b(siluf(a));
}

// ---------------- selective scan: one thread per (b,e), B/C staged in LDS ----------------
__global__ __launch_bounds__(256) void scan_k(u16* __restrict__ dy, const u16* __restrict__ xc,
                                              const float* __restrict__ dbc, const float* __restrict__ A_log){
  __shared__ float sB[16], sC[16];
  int b = blockIdx.x >> 3;
  int e = (blockIdx.x & 7)*256 + threadIdx.x;
  float A[16], h[16];
  #pragma unroll
  for (int n = 0; n < 16; n++){ A[n] = -expf(A_log[(size_t)e*DSTATE + n]); h[n] = 0.f; }
  int base = b*SLEN;
  for (int l = 0; l < SLEN; l++){
    int r = base + l;
    if (threadIdx.x < 32){
      float v = dbc[r*96 + 64 + threadIdx.x];
      if (threadIdx.x < 16) sB[threadIdx.x] = v;
      else                  sC[threadIdx.x - 16] = v;
    }
    __syncthreads();
    float dv = b2f(dy[(size_t)r*DINNER + e]);
    float xv = b2f(xc[(size_t)r*DINNER + e]);
    float dx = dv * xv;
    float y = 0.f;
    #pragma unroll
    for (int n = 0; n < 16; n++){
      h[n] = expf(dv*A[n])*h[n] + dx*sB[n];
      y += h[n]*sC[n];
    }
    dy[(size_t)r*DINNER + e] = f2b(y);
    __syncthreads();
  }
}

// ---------------- gate: y = (y + xc*Dp)*silu(z), rows l>=196 ----------------
__global__ __launch_bounds__(256) void gate_k(u16* __restrict__ y, const u16* __restrict__ xc,
                                              const u16* __restrict__ zb, const float* __restrict__ Dp){
  int idx = blockIdx.x*256 + threadIdx.x;
  int e = idx & (DINNER-1);
  int t = (idx >> 11) % TLEN;
  int b = idx / (TLEN*DINNER);
  int r = b*SLEN + TLEN + t;
  float zv = b2f(zb[((size_t)b*TLEN + t)*DINNER + e]);
  float yv = b2f(y[(size_t)r*DINNER + e]) + b2f(xc[(size_t)r*DINNER + e])*Dp[e];
  y[(size_t)r*DINNER + e] = f2b(yv * siluf(zv));
}

// ---------------- final residual + LN -> *** f32 *** out ----------------
__global__ __launch_bounds__(256) void final_k(const u16* __restrict__ seqb, const float* __restrict__ mix,
                                               const float* __restrict__ g, const float* __restrict__ bb,
                                               float* __restrict__ out){
  __shared__ float r1[256], r2[256];
  int ro = blockIdx.x; int b = ro / TLEN;
  int rr = ro + TLEN*(b+1);
  int tid = threadIdx.x;
  float v[4]; float s = 0.f, s2 = 0.f;
  for (int i = 0; i < 4; i++){
    int d = tid + i*256;
    float val = b2f(seqb[(size_t)rr*DMODEL + d]) + mix[(size_t)ro*DMODEL + d];
    v[i] = val; s += val; s2 += val*val;
  }
  r1[tid] = s; r2[tid] = s2; __syncthreads();
  for (int st = 128; st > 0; st >>= 1){
    if (tid < st){ r1[tid]+=r1[tid+st]; r2[tid]+=r2[tid+st]; }
    __syncthreads();
  }
  float mu = r1[0]/1024.f;
  float var = r2[0]/1024.f - mu*mu;
  float rs = rsqrtf(var + 1e-5f);
  for (int i = 0; i < 4; i++){
    int d = tid + i*256;
    out[(size_t)ro*DMODEL + d] = (v[i]-mu)*rs*g[d] + bb[d];
  }
}

extern "C" void kernel_launch(void* const* d_in, const int* in_sizes, int n_in,
                              void* d_out, int out_size, void* d_ws, size_t ws_size,
                              hipStream_t stream){
  const float* x_r       = (const float*)d_in[0];   // canonical order restored
  const int*   timesteps = (const int*)d_in[1];
  const float* motion    = (const float*)d_in[2];
  const float* time_w1   = (const float*)d_in[3];
  const float* time_b1   = (const float*)d_in[4];
  const float* time_w2   = (const float*)d_in[5];
  const float* time_b2   = (const float*)d_in[6];
  const float* pos_emb   = (const float*)d_in[7];
  const float* ln_g      = (const float*)d_in[8];
  const float* ln_b      = (const float*)d_in[9];
  const float* in_proj_w = (const float*)d_in[10];
  const float* conv_w    = (const float*)d_in[11];
  const float* conv_b    = (const float*)d_in[12];
  const float* x_proj_w  = (const float*)d_in[13];
  const float* dt_proj_w = (const float*)d_in[14];
  const float* dt_proj_b = (const float*)d_in[15];
  const float* A_log     = (const float*)d_in[16];
  const float* Dp        = (const float*)d_in[17];
  const float* out_proj_w= (const float*)d_in[18];
  const float* rms_w     = (const float*)d_in[19];
  float* out = (float*)d_out;                       // *** f32 output ***

  float* w = (float*)d_ws;
  const size_t o_temb = 0;
  const size_t o_hmid = o_temb + 4096;
  const size_t o_embt = o_hmid + 8192;
  const size_t o_rstd = o_embt + 4096;
  const size_t o_dbc  = o_rstd + 2048;
  const size_t o_mix  = o_dbc  + (size_t)BSZ*SLEN*96;
  const size_t f32_end= o_mix  + (size_t)BSZ*TLEN*DMODEL;
  u16* ub    = (u16*)(w + f32_end);
  u16* seqb  = ub;
  u16* xcpre = seqb  + (size_t)BSZ*SLEN*DMODEL;
  u16* zb    = xcpre + (size_t)BSZ*SLEN*DINNER;
  u16* xc    = zb    + (size_t)BSZ*TLEN*DINNER;
  u16* yb    = xcpre;                               // reuse after conv
  const size_t needed = f32_end*sizeof(float)
                      + (size_t)(1605632 + 3211264 + 1605632 + 3211264)*sizeof(u16);
  if (ws_size < needed){                            // sig: zeros (absmax 4.90625)
    zero_out_k<<<(out_size + 255)/256, 256, 0, stream>>>(out, out_size);
    return;
  }

  temb_k<<<8, 256, 0, stream>>>(timesteps, w + o_temb);
  mlp_k<<<2048, 256, 0, stream>>>(w + o_temb, time_w1, time_b1, w + o_hmid, 1024, 2048, 1);
  mlp_k<<<1024, 256, 0, stream>>>(w + o_hmid, time_w2, time_b2, w + o_embt, 2048, 1024, 0);
  build_seq_k<<<BSZ*SLEN, 256, 0, stream>>>(x_r, motion, pos_emb, w + o_embt, ln_g, ln_b,
                                            seqb, w + o_rstd);
  gemm_k<0,1,1><<<dim3(64, 25), 256, 0, stream>>>(seqb, DMODEL, BSZ*SLEN, DMODEL,
                                                  in_proj_w, 2*DINNER, xcpre, DINNER,
                                                  w + o_rstd, rms_w, nullptr, zb);
  conv_k<<<(BSZ*SLEN*DINNER)/256, 256, 0, stream>>>(xcpre, conv_w, conv_b, xc);
  gemm_k<1,1,0><<<dim3(2, 25), 256, 0, stream>>>(xc, DINNER, BSZ*SLEN, DINNER,
                                                 x_proj_w, 96, w + o_dbc, 96,
                                                 nullptr, nullptr, nullptr, nullptr);
  gemm_k<2,0,1><<<dim3(32, 25), 256, 0, stream>>>(w + o_dbc, 96, BSZ*SLEN, DTRANK,
                                                  dt_proj_w, DINNER, yb, DINNER,
                                                  nullptr, nullptr, dt_proj_b, nullptr);
  scan_k<<<BSZ*8, 256, 0, stream>>>(yb, xc, w + o_dbc, A_log);
  gate_k<<<(BSZ*TLEN*DINNER)/256, 256, 0, stream>>>(yb, xc, zb, Dp);
  gemm_k<3,1,0><<<dim3(16, 13), 256, 0, stream>>>(yb, DINNER, BSZ*TLEN, DINNER,
                                                  out_proj_w, DMODEL, w + o_mix, DMODEL,
                                                  nullptr, nullptr, nullptr, nullptr);
  final_k<<<BSZ*TLEN, 256, 0, stream>>>(seqb, w + o_mix, ln_g, ln_b, out);
}

// Round 11
// 780.719 us; speedup vs baseline: 1.4323x; 1.4323x over previous
//
#include <hip/hip_runtime.h>
#include <cmath>

#define BSZ 4
#define TLEN 196
#define SLEN 392
#define DMODEL 1024
#define DINNER 2048
#define DSTATE 16
#define DTRANK 64

typedef unsigned short u16;

static __device__ __forceinline__ float b2f(u16 u){
  union { unsigned int i; float f; } v; v.i = ((unsigned int)u) << 16; return v.f;
}
static __device__ __forceinline__ u16 f2b(float f){
  unsigned int x = __float_as_uint(f);
  unsigned int r = (x + 0x7fffu + ((x >> 16) & 1u)) >> 16;
  return (u16)r;
}
static __device__ __forceinline__ float siluf(float x){ return x / (1.f + expf(-x)); }
static __device__ __forceinline__ float softplusf(float x){
  return (x > 20.f) ? x : log1pf(expf(x));
}

__global__ void zero_out_k(float* __restrict__ out, int n){
  int i = blockIdx.x*256 + threadIdx.x;
  if (i < n) out[i] = 0.f;
}

// ---------------- 1. timestep embedding ----------------
__global__ __launch_bounds__(256) void temb_k(const int* __restrict__ ts, float* __restrict__ temb){
  int i = blockIdx.x*256 + threadIdx.x;           // 2048
  if (i >= BSZ*512) return;
  int b = i >> 9, k = i & 511;
  float fr = expf(-9.210340371976184f * (float)k / 512.0f);
  float arg = (float)ts[b] * fr;
  temb[b*1024 + k]       = cosf(arg);
  temb[b*1024 + 512 + k] = sinf(arg);
}

// ---------------- 2. small time-MLP layer (4 rows) ----------------
__global__ __launch_bounds__(256) void mlp_k(const float* __restrict__ src, const float* __restrict__ W,
                                             const float* __restrict__ bias, float* __restrict__ dst,
                                             int K, int N, int act){
  __shared__ float s[4*2048];
  __shared__ float4 red[256];
  int tid = threadIdx.x; int e = blockIdx.x;
  for (int i = tid; i < 4*K; i += 256) s[i] = src[i];
  __syncthreads();
  float a0=0,a1=0,a2=0,a3=0;
  for (int d = tid; d < K; d += 256){
    float w = W[(size_t)e*K + d];
    a0 += w*s[d]; a1 += w*s[K+d]; a2 += w*s[2*K+d]; a3 += w*s[3*K+d];
  }
  red[tid] = make_float4(a0,a1,a2,a3);
  __syncthreads();
  for (int st = 128; st > 0; st >>= 1){
    if (tid < st){
      float4 o = red[tid+st]; float4 m = red[tid];
      m.x+=o.x; m.y+=o.y; m.z+=o.z; m.w+=o.w; red[tid]=m;
    }
    __syncthreads();
  }
  if (tid == 0){
    float bs = bias[e];
    float4 v = red[0];
    float vv[4] = {v.x, v.y, v.z, v.w};
    for (int b = 0; b < 4; b++){
      float x = vv[b] + bs;
      if (act) x = siluf(x);
      dst[b*N + e] = x;
    }
  }
}

// ---------------- 3. build seq (LN -> bf16) + rms rstd ----------------
__global__ __launch_bounds__(256) void build_seq_k(const float* __restrict__ x_r, const float* __restrict__ motion,
                                                   const float* __restrict__ pos, const float* __restrict__ embt,
                                                   const float* __restrict__ g, const float* __restrict__ bb,
                                                   u16* __restrict__ seqb, float* __restrict__ rstd){
  __shared__ float r1[256], r2[256];
  int r = blockIdx.x; int b = r / SLEN; int l = r % SLEN;
  int tid = threadIdx.x;
  float v[4]; float s = 0.f, s2 = 0.f;
  int lp = (l < TLEN) ? l : l - TLEN;
  for (int i = 0; i < 4; i++){
    int d = tid + i*256;
    float val = pos[(size_t)lp*DMODEL + d];
    if (l < TLEN) val += motion[((size_t)b*TLEN + l)*DMODEL + d];
    else          val += x_r[((size_t)b*TLEN + (l-TLEN))*DMODEL + d] + embt[(size_t)b*DMODEL + d];
    v[i] = val; s += val; s2 += val*val;
  }
  r1[tid] = s; r2[tid] = s2; __syncthreads();
  for (int st = 128; st > 0; st >>= 1){
    if (tid < st){ r1[tid]+=r1[tid+st]; r2[tid]+=r2[tid+st]; }
    __syncthreads();
  }
  float mu = r1[0]/1024.f;
  float var = r2[0]/1024.f - mu*mu;
  float rs = rsqrtf(var + 1e-5f);
  __syncthreads();
  float q = 0.f;
  for (int i = 0; i < 4; i++){
    int d = tid + i*256;
    float yv = (v[i]-mu)*rs*g[d] + bb[d];
    seqb[(size_t)r*DMODEL + d] = f2b(yv);
    q += yv*yv;
  }
  r1[tid] = q; __syncthreads();
  for (int st = 128; st > 0; st >>= 1){
    if (tid < st) r1[tid]+=r1[tid+st];
    __syncthreads();
  }
  if (tid == 0) rstd[r] = rsqrtf(r1[0]/1024.f + 1e-5f);
}

// ---------------- tiled GEMM (unchanged; MFMA conversion next round) ----------------
template<int MODE, int AF, int CF>
__global__ __launch_bounds__(256) void gemm_k(const void* __restrict__ Ap, int lda, int M, int K,
                                              const float* __restrict__ W, int N,
                                              void* __restrict__ Cp, int ldc,
                                              const float* __restrict__ rowScale,
                                              const float* __restrict__ colScale,
                                              const float* __restrict__ bias,
                                              u16* __restrict__ Z2){
  __shared__ float As[16][68];
  __shared__ float Ws[16][68];
  const float* Af = (const float*)Ap;
  const u16*   Au = (const u16*)Ap;
  float* Cf = (float*)Cp;
  u16*   Cu = (u16*)Cp;
  int tid = threadIdx.x;
  int ntile = blockIdx.x, mtile = blockIdx.y;
  int m_l = tid >> 2, kq = (tid & 3) << 2;
  float acc[4][4] = {};
  int m0 = (tid & 15) << 2;
  int n0 = (tid >> 4) << 2;

  for (int k0 = 0; k0 < K; k0 += 16){
    int row = mtile*64 + m_l;
    float4 av = make_float4(0.f,0.f,0.f,0.f);
    if (row < M){
      size_t rr = row;
      if (MODE == 3) rr = row + 196*(row/196 + 1);
      if (AF == 0){
        av = *(const float4*)(Af + rr*(size_t)lda + k0 + kq);
      } else {
        ushort4 u = *(const ushort4*)(Au + rr*(size_t)lda + k0 + kq);
        av.x=b2f(u.x); av.y=b2f(u.y); av.z=b2f(u.z); av.w=b2f(u.w);
      }
      if (MODE == 0){
        float rsv = rowScale[row];
        av.x *= rsv * colScale[k0+kq+0];
        av.y *= rsv * colScale[k0+kq+1];
        av.z *= rsv * colScale[k0+kq+2];
        av.w *= rsv * colScale[k0+kq+3];
      }
    }
    As[kq+0][m_l]=av.x; As[kq+1][m_l]=av.y; As[kq+2][m_l]=av.z; As[kq+3][m_l]=av.w;

    int n = ntile*64 + m_l;
    float4 wv = make_float4(0.f,0.f,0.f,0.f);
    if (n < N) wv = *(const float4*)(W + (size_t)n*K + k0 + kq);
    Ws[kq+0][m_l]=wv.x; Ws[kq+1][m_l]=wv.y; Ws[kq+2][m_l]=wv.z; Ws[kq+3][m_l]=wv.w;
    __syncthreads();

    #pragma unroll
    for (int k = 0; k < 16; k++){
      float4 a = *(const float4*)&As[k][m0];
      float4 b = *(const float4*)&Ws[k][n0];
      acc[0][0]+=a.x*b.x; acc[0][1]+=a.x*b.y; acc[0][2]+=a.x*b.z; acc[0][3]+=a.x*b.w;
      acc[1][0]+=a.y*b.x; acc[1][1]+=a.y*b.y; acc[1][2]+=a.y*b.z; acc[1][3]+=a.y*b.w;
      acc[2][0]+=a.z*b.x; acc[2][1]+=a.z*b.y; acc[2][2]+=a.z*b.z; acc[2][3]+=a.z*b.w;
      acc[3][0]+=a.w*b.x; acc[3][1]+=a.w*b.y; acc[3][2]+=a.w*b.z; acc[3][3]+=a.w*b.w;
    }
    __syncthreads();
  }

  #pragma unroll
  for (int i = 0; i < 4; i++){
    int row = mtile*64 + (tid & 15)*4 + i;
    if (row >= M) continue;
    #pragma unroll
    for (int j = 0; j < 4; j++){
      int col = ntile*64 + (tid >> 4)*4 + j;
      if (col >= N) continue;
      float val = acc[i][j];
      if (MODE == 0){
        if (col < DINNER){
          Cu[(size_t)row*DINNER + col] = f2b(val);
        } else {
          int l = row % SLEN;
          if (l >= TLEN){
            int b = row / SLEN;
            Z2[((size_t)(b*TLEN + (l - TLEN)))*DINNER + (col - DINNER)] = f2b(val);
          }
        }
      } else {
        if (MODE == 2) val = softplusf(val + bias[col]);
        if (CF == 0) Cf[(size_t)row*ldc + col] = val;
        else         Cu[(size_t)row*ldc + col] = f2b(val);
      }
    }
  }
}

// ---------------- depthwise causal conv(4) + bias + silu ----------------
__global__ __launch_bounds__(256) void conv_k(const u16* __restrict__ xpre, const float* __restrict__ cw,
                                              const float* __restrict__ cb, u16* __restrict__ xc){
  int idx = blockIdx.x*256 + threadIdx.x;
  int e = idx & (DINNER-1);
  int l = (idx >> 11) % SLEN;
  int b = idx / (SLEN*DINNER);
  float a = cb[e];
  #pragma unroll
  for (int k = 0; k < 4; k++){
    int li = l - 3 + k;
    if (li >= 0) a += cw[e*4 + k] * b2f(xpre[((size_t)(b*SLEN + li))*DINNER + e]);
  }
  xc[((size_t)(b*SLEN + l))*DINNER + e] = f2b(siluf(a));
}

// ---------------- selective scan v2: whole-sequence B/C in LDS, 1 barrier, pipelined loads ----
// block = 256 threads = 256 channels; grid = BSZ * (DINNER/256) = 32 blocks
__global__ __launch_bounds__(256) void scan_k(u16* __restrict__ dy, const u16* __restrict__ xc,
                                              const float* __restrict__ dbc, const float* __restrict__ A_log){
  __shared__ float sB[SLEN*16];   // 25088 B
  __shared__ float sC[SLEN*16];   // 25088 B
  int b = blockIdx.x >> 3;
  int e = (blockIdx.x & 7)*256 + threadIdx.x;
  int base = b*SLEN;
  // one-time cooperative stage of all B/C for this batch's sequence
  for (int i = threadIdx.x; i < SLEN*32; i += 256){
    int l = i >> 5, n = i & 31;
    float v = dbc[(size_t)(base + l)*96 + 64 + n];
    if (n < 16) sB[l*16 + n] = v;
    else        sC[l*16 + (n - 16)] = v;
  }
  float A[16], h[16];
  #pragma unroll
  for (int n = 0; n < 16; n++){ A[n] = -__expf(A_log[(size_t)e*DSTATE + n]); h[n] = 0.f; }
  __syncthreads();

  size_t idx = (size_t)base*DINNER + e;
  float dv = b2f(dy[idx]);
  float xv = b2f(xc[idx]);
  for (int l = 0; l < SLEN; l++){
    // prefetch next step (clamped at the end to stay in-bounds)
    size_t nidx = (l+1 < SLEN) ? idx + DINNER : idx;
    float dv_n = b2f(dy[nidx]);
    float xv_n = b2f(xc[nidx]);
    float dx = dv * xv;
    const float* Bl = &sB[l*16];
    const float* Cl = &sC[l*16];
    float y = 0.f;
    #pragma unroll
    for (int n = 0; n < 16; n++){
      h[n] = __expf(dv*A[n])*h[n] + dx*Bl[n];
      y += h[n]*Cl[n];
    }
    dy[idx] = f2b(y);
    idx += DINNER;
    dv = dv_n; xv = xv_n;
  }
}

// ---------------- gate: y = (y + xc*Dp)*silu(z), rows l>=196 ----------------
__global__ __launch_bounds__(256) void gate_k(u16* __restrict__ y, const u16* __restrict__ xc,
                                              const u16* __restrict__ zb, const float* __restrict__ Dp){
  int idx = blockIdx.x*256 + threadIdx.x;
  int e = idx & (DINNER-1);
  int t = (idx >> 11) % TLEN;
  int b = idx / (TLEN*DINNER);
  int r = b*SLEN + TLEN + t;
  float zv = b2f(zb[((size_t)b*TLEN + t)*DINNER + e]);
  float yv = b2f(y[(size_t)r*DINNER + e]) + b2f(xc[(size_t)r*DINNER + e])*Dp[e];
  y[(size_t)r*DINNER + e] = f2b(yv * siluf(zv));
}

// ---------------- final residual + LN -> f32 out ----------------
__global__ __launch_bounds__(256) void final_k(const u16* __restrict__ seqb, const float* __restrict__ mix,
                                               const float* __restrict__ g, const float* __restrict__ bb,
                                               float* __restrict__ out){
  __shared__ float r1[256], r2[256];
  int ro = blockIdx.x; int b = ro / TLEN;
  int rr = ro + TLEN*(b+1);
  int tid = threadIdx.x;
  float v[4]; float s = 0.f, s2 = 0.f;
  for (int i = 0; i < 4; i++){
    int d = tid + i*256;
    float val = b2f(seqb[(size_t)rr*DMODEL + d]) + mix[(size_t)ro*DMODEL + d];
    v[i] = val; s += val; s2 += val*val;
  }
  r1[tid] = s; r2[tid] = s2; __syncthreads();
  for (int st = 128; st > 0; st >>= 1){
    if (tid < st){ r1[tid]+=r1[tid+st]; r2[tid]+=r2[tid+st]; }
    __syncthreads();
  }
  float mu = r1[0]/1024.f;
  float var = r2[0]/1024.f - mu*mu;
  float rs = rsqrtf(var + 1e-5f);
  for (int i = 0; i < 4; i++){
    int d = tid + i*256;
    out[(size_t)ro*DMODEL + d] = (v[i]-mu)*rs*g[d] + bb[d];
  }
}

extern "C" void kernel_launch(void* const* d_in, const int* in_sizes, int n_in,
                              void* d_out, int out_size, void* d_ws, size_t ws_size,
                              hipStream_t stream){
  const float* x_r       = (const float*)d_in[0];
  const int*   timesteps = (const int*)d_in[1];
  const float* motion    = (const float*)d_in[2];
  const float* time_w1   = (const float*)d_in[3];
  const float* time_b1   = (const float*)d_in[4];
  const float* time_w2   = (const float*)d_in[5];
  const float* time_b2   = (const float*)d_in[6];
  const float* pos_emb   = (const float*)d_in[7];
  const float* ln_g      = (const float*)d_in[8];
  const float* ln_b      = (const float*)d_in[9];
  const float* in_proj_w = (const float*)d_in[10];
  const float* conv_w    = (const float*)d_in[11];
  const float* conv_b    = (const float*)d_in[12];
  const float* x_proj_w  = (const float*)d_in[13];
  const float* dt_proj_w = (const float*)d_in[14];
  const float* dt_proj_b = (const float*)d_in[15];
  const float* A_log     = (const float*)d_in[16];
  const float* Dp        = (const float*)d_in[17];
  const float* out_proj_w= (const float*)d_in[18];
  const float* rms_w     = (const float*)d_in[19];
  float* out = (float*)d_out;

  float* w = (float*)d_ws;
  const size_t o_temb = 0;
  const size_t o_hmid = o_temb + 4096;
  const size_t o_embt = o_hmid + 8192;
  const size_t o_rstd = o_embt + 4096;
  const size_t o_dbc  = o_rstd + 2048;
  const size_t o_mix  = o_dbc  + (size_t)BSZ*SLEN*96;
  const size_t f32_end= o_mix  + (size_t)BSZ*TLEN*DMODEL;
  u16* ub    = (u16*)(w + f32_end);
  u16* seqb  = ub;
  u16* xcpre = seqb  + (size_t)BSZ*SLEN*DMODEL;
  u16* zb    = xcpre + (size_t)BSZ*SLEN*DINNER;
  u16* xc    = zb    + (size_t)BSZ*TLEN*DINNER;
  u16* yb    = xcpre;                               // reuse after conv
  const size_t needed = f32_end*sizeof(float)
                      + (size_t)(1605632 + 3211264 + 1605632 + 3211264)*sizeof(u16);
  if (ws_size < needed){
    zero_out_k<<<(out_size + 255)/256, 256, 0, stream>>>(out, out_size);
    return;
  }

  temb_k<<<8, 256, 0, stream>>>(timesteps, w + o_temb);
  mlp_k<<<2048, 256, 0, stream>>>(w + o_temb, time_w1, time_b1, w + o_hmid, 1024, 2048, 1);
  mlp_k<<<1024, 256, 0, stream>>>(w + o_hmid, time_w2, time_b2, w + o_embt, 2048, 1024, 0);
  build_seq_k<<<BSZ*SLEN, 256, 0, stream>>>(x_r, motion, pos_emb, w + o_embt, ln_g, ln_b,
                                            seqb, w + o_rstd);
  gemm_k<0,1,1><<<dim3(64, 25), 256, 0, stream>>>(seqb, DMODEL, BSZ*SLEN, DMODEL,
                                                  in_proj_w, 2*DINNER, xcpre, DINNER,
                                                  w + o_rstd, rms_w, nullptr, zb);
  conv_k<<<(BSZ*SLEN*DINNER)/256, 256, 0, stream>>>(xcpre, conv_w, conv_b, xc);
  gemm_k<1,1,0><<<dim3(2, 25), 256, 0, stream>>>(xc, DINNER, BSZ*SLEN, DINNER,
                                                 x_proj_w, 96, w + o_dbc, 96,
                                                 nullptr, nullptr, nullptr, nullptr);
  gemm_k<2,0,1><<<dim3(32, 25), 256, 0, stream>>>(w + o_dbc, 96, BSZ*SLEN, DTRANK,
                                                  dt_proj_w, DINNER, yb, DINNER,
                                                  nullptr, nullptr, dt_proj_b, nullptr);
  scan_k<<<BSZ*8, 256, 0, stream>>>(yb, xc, w + o_dbc, A_log);
  gate_k<<<(BSZ*TLEN*DINNER)/256, 256, 0, stream>>>(yb, xc, zb, Dp);
  gemm_k<3,1,0><<<dim3(16, 13), 256, 0, stream>>>(yb, DINNER, BSZ*TLEN, DINNER,
                                                  out_proj_w, DMODEL, w + o_mix, DMODEL,
                                                  nullptr, nullptr, nullptr, nullptr);
  final_k<<<BSZ*TLEN, 256, 0, stream>>>(seqb, w + o_mix, ln_g, ln_b, out);
}

// Round 12
// 571.252 us; speedup vs baseline: 1.9575x; 1.3667x over previous
//
#include <hip/hip_runtime.h>
#include <cmath>

#define BSZ 4
#define TLEN 196
#define SLEN 392
#define DMODEL 1024
#define DINNER 2048
#define DSTATE 16
#define DTRANK 64

typedef unsigned short u16;
typedef __attribute__((ext_vector_type(8))) short bf16x8;
typedef __attribute__((ext_vector_type(4))) float f32x4;

static __device__ __forceinline__ float b2f(u16 u){
  union { unsigned int i; float f; } v; v.i = ((unsigned int)u) << 16; return v.f;
}
static __device__ __forceinline__ u16 f2b(float f){
  unsigned int x = __float_as_uint(f);
  unsigned int r = (x + 0x7fffu + ((x >> 16) & 1u)) >> 16;
  return (u16)r;
}
static __device__ __forceinline__ float siluf(float x){ return x / (1.f + expf(-x)); }
static __device__ __forceinline__ float softplusf(float x){
  return (x > 20.f) ? x : log1pf(expf(x));
}

__global__ void zero_out_k(float* __restrict__ out, int n){
  int i = blockIdx.x*256 + threadIdx.x;
  if (i < n) out[i] = 0.f;
}

// ---------------- 1. timestep embedding ----------------
__global__ __launch_bounds__(256) void temb_k(const int* __restrict__ ts, float* __restrict__ temb){
  int i = blockIdx.x*256 + threadIdx.x;
  if (i >= BSZ*512) return;
  int b = i >> 9, k = i & 511;
  float fr = expf(-9.210340371976184f * (float)k / 512.0f);
  float arg = (float)ts[b] * fr;
  temb[b*1024 + k]       = cosf(arg);
  temb[b*1024 + 512 + k] = sinf(arg);
}

// ---------------- 2. small time-MLP layer (4 rows) ----------------
__global__ __launch_bounds__(256) void mlp_k(const float* __restrict__ src, const float* __restrict__ W,
                                             const float* __restrict__ bias, float* __restrict__ dst,
                                             int K, int N, int act){
  __shared__ float s[4*2048];
  __shared__ float4 red[256];
  int tid = threadIdx.x; int e = blockIdx.x;
  for (int i = tid; i < 4*K; i += 256) s[i] = src[i];
  __syncthreads();
  float a0=0,a1=0,a2=0,a3=0;
  for (int d = tid; d < K; d += 256){
    float w = W[(size_t)e*K + d];
    a0 += w*s[d]; a1 += w*s[K+d]; a2 += w*s[2*K+d]; a3 += w*s[3*K+d];
  }
  red[tid] = make_float4(a0,a1,a2,a3);
  __syncthreads();
  for (int st = 128; st > 0; st >>= 1){
    if (tid < st){
      float4 o = red[tid+st]; float4 m = red[tid];
      m.x+=o.x; m.y+=o.y; m.z+=o.z; m.w+=o.w; red[tid]=m;
    }
    __syncthreads();
  }
  if (tid == 0){
    float bs = bias[e];
    float4 v = red[0];
    float vv[4] = {v.x, v.y, v.z, v.w};
    for (int b = 0; b < 4; b++){
      float x = vv[b] + bs;
      if (act) x = siluf(x);
      dst[b*N + e] = x;
    }
  }
}

// ---------------- 3. build seq (LN -> bf16) + rms rstd ----------------
__global__ __launch_bounds__(256) void build_seq_k(const float* __restrict__ x_r, const float* __restrict__ motion,
                                                   const float* __restrict__ pos, const float* __restrict__ embt,
                                                   const float* __restrict__ g, const float* __restrict__ bb,
                                                   u16* __restrict__ seqb, float* __restrict__ rstd){
  __shared__ float r1[256], r2[256];
  int r = blockIdx.x; int b = r / SLEN; int l = r % SLEN;
  int tid = threadIdx.x;
  float v[4]; float s = 0.f, s2 = 0.f;
  int lp = (l < TLEN) ? l : l - TLEN;
  for (int i = 0; i < 4; i++){
    int d = tid + i*256;
    float val = pos[(size_t)lp*DMODEL + d];
    if (l < TLEN) val += motion[((size_t)b*TLEN + l)*DMODEL + d];
    else          val += x_r[((size_t)b*TLEN + (l-TLEN))*DMODEL + d] + embt[(size_t)b*DMODEL + d];
    v[i] = val; s += val; s2 += val*val;
  }
  r1[tid] = s; r2[tid] = s2; __syncthreads();
  for (int st = 128; st > 0; st >>= 1){
    if (tid < st){ r1[tid]+=r1[tid+st]; r2[tid]+=r2[tid+st]; }
    __syncthreads();
  }
  float mu = r1[0]/1024.f;
  float var = r2[0]/1024.f - mu*mu;
  float rs = rsqrtf(var + 1e-5f);
  __syncthreads();
  float q = 0.f;
  for (int i = 0; i < 4; i++){
    int d = tid + i*256;
    float yv = (v[i]-mu)*rs*g[d] + bb[d];
    seqb[(size_t)r*DMODEL + d] = f2b(yv);
    q += yv*yv;
  }
  r1[tid] = q; __syncthreads();
  for (int st = 128; st > 0; st >>= 1){
    if (tid < st) r1[tid]+=r1[tid+st];
    __syncthreads();
  }
  if (tid == 0) rstd[r] = rsqrtf(r1[0]/1024.f + 1e-5f);
}

// ======== MFMA bf16 GEMM: C[M,N] = A[M,K](bf16) * W[N,K](f32->bf16)^T ========
// MODE 0: in_proj — A scaled by rstd[row]*rmsw[k] during staging; cols<2048 -> Cu2 bf16,
//         cols>=2048 -> Z2 (z, rows l>=196 only)
// MODE 3: out_proj — A row remapped (rr = row + 196*(row/196+1)); C f32
// tile 64x64, BK=32, 4 waves; LDS in fragment order [quad][row][8]
template<int MODE>
__global__ __launch_bounds__(256) void mgemm_k(const u16* __restrict__ A, int lda, int M, int K,
                                               const float* __restrict__ W, int N,
                                               void* __restrict__ Cp, int ldc,
                                               const float* __restrict__ rstd,
                                               const float* __restrict__ rmsw,
                                               u16* __restrict__ Cu2, u16* __restrict__ Z2){
  __shared__ __align__(16) u16 Asl[4][64][8];
  __shared__ __align__(16) u16 Wsl[4][64][8];
  int tid  = threadIdx.x;
  int ntile = blockIdx.x, mtile = blockIdx.y;
  int wave = tid >> 6, lane = tid & 63;
  int m16 = lane & 15, quad = lane >> 4;

  int srow = tid >> 2;              // 0..63
  int sq   = tid & 3;               // quad slot for staging
  int skq  = sq << 3;               // 0,8,16,24
  int aRow = mtile*64 + srow;
  bool aValid = aRow < M;
  size_t rr = aRow;
  if (MODE == 3) rr = (size_t)aRow + 196*(aRow/196 + 1);
  float rsv = (MODE == 0 && aValid) ? rstd[aRow] : 0.f;
  const u16* Abase = A + rr*(size_t)lda + skq;
  const float* Wbase = W + (size_t)(ntile*64 + srow)*K + skq;   // N exact multiple of 64

  f32x4 acc[4];
  #pragma unroll
  for (int s = 0; s < 4; s++) acc[s] = (f32x4){0.f,0.f,0.f,0.f};

  for (int k0 = 0; k0 < K; k0 += 32){
    // ---- stage A (bf16, optional rms scaling) ----
    u16 t8[8] = {0,0,0,0,0,0,0,0};
    if (aValid){
      ushort4 u0 = *(const ushort4*)(Abase + k0);
      ushort4 u1 = *(const ushort4*)(Abase + k0 + 4);
      t8[0]=u0.x; t8[1]=u0.y; t8[2]=u0.z; t8[3]=u0.w;
      t8[4]=u1.x; t8[5]=u1.y; t8[6]=u1.z; t8[7]=u1.w;
      if (MODE == 0){
        #pragma unroll
        for (int j = 0; j < 8; j++) t8[j] = f2b(b2f(t8[j]) * rsv * rmsw[k0 + skq + j]);
      }
    }
    ushort4* ad = (ushort4*)&Asl[sq][srow][0];
    ad[0] = make_ushort4(t8[0],t8[1],t8[2],t8[3]);
    ad[1] = make_ushort4(t8[4],t8[5],t8[6],t8[7]);
    // ---- stage W (f32 -> bf16) ----
    float4 w0 = *(const float4*)(Wbase + k0);
    float4 w1 = *(const float4*)(Wbase + k0 + 4);
    ushort4* wd = (ushort4*)&Wsl[sq][srow][0];
    wd[0] = make_ushort4(f2b(w0.x),f2b(w0.y),f2b(w0.z),f2b(w0.w));
    wd[1] = make_ushort4(f2b(w1.x),f2b(w1.y),f2b(w1.z),f2b(w1.w));
    __syncthreads();

    bf16x8 af = *(const bf16x8*)&Asl[quad][wave*16 + m16][0];
    #pragma unroll
    for (int s = 0; s < 4; s++){
      bf16x8 bf = *(const bf16x8*)&Wsl[quad][s*16 + m16][0];
      acc[s] = __builtin_amdgcn_mfma_f32_16x16x32_bf16(af, bf, acc[s], 0, 0, 0);
    }
    __syncthreads();
  }

  // ---- epilogue ----
  #pragma unroll
  for (int s = 0; s < 4; s++){
    #pragma unroll
    for (int r = 0; r < 4; r++){
      int m = mtile*64 + wave*16 + quad*4 + r;
      if (m >= M) continue;
      int n = ntile*64 + s*16 + m16;
      float val = acc[s][r];
      if (MODE == 0){
        if (n < DINNER){
          Cu2[(size_t)m*DINNER + n] = f2b(val);
        } else {
          int l = m % SLEN;
          if (l >= TLEN){
            int b = m / SLEN;
            Z2[((size_t)(b*TLEN + (l - TLEN)))*DINNER + (n - DINNER)] = f2b(val);
          }
        }
      } else {
        ((float*)Cp)[(size_t)m*ldc + n] = val;
      }
    }
  }
}

// ---------------- fp32 tiled GEMM (kept for x_proj / dt_proj) ----------------
// MODE 1: x_proj (A bf16 -> C f32). MODE 2: dt_proj (A f32 -> softplus(+bias) -> C bf16)
template<int MODE, int AF, int CF>
__global__ __launch_bounds__(256) void gemm_k(const void* __restrict__ Ap, int lda, int M, int K,
                                              const float* __restrict__ W, int N,
                                              void* __restrict__ Cp, int ldc,
                                              const float* __restrict__ bias){
  __shared__ float As[16][68];
  __shared__ float Ws[16][68];
  const float* Af = (const float*)Ap;
  const u16*   Au = (const u16*)Ap;
  float* Cf = (float*)Cp;
  u16*   Cu = (u16*)Cp;
  int tid = threadIdx.x;
  int ntile = blockIdx.x, mtile = blockIdx.y;
  int m_l = tid >> 2, kq = (tid & 3) << 2;
  float acc[4][4] = {};
  int m0 = (tid & 15) << 2;
  int n0 = (tid >> 4) << 2;

  for (int k0 = 0; k0 < K; k0 += 16){
    int row = mtile*64 + m_l;
    float4 av = make_float4(0.f,0.f,0.f,0.f);
    if (row < M){
      if (AF == 0){
        av = *(const float4*)(Af + (size_t)row*lda + k0 + kq);
      } else {
        ushort4 u = *(const ushort4*)(Au + (size_t)row*lda + k0 + kq);
        av.x=b2f(u.x); av.y=b2f(u.y); av.z=b2f(u.z); av.w=b2f(u.w);
      }
    }
    As[kq+0][m_l]=av.x; As[kq+1][m_l]=av.y; As[kq+2][m_l]=av.z; As[kq+3][m_l]=av.w;

    int n = ntile*64 + m_l;
    float4 wv = make_float4(0.f,0.f,0.f,0.f);
    if (n < N) wv = *(const float4*)(W + (size_t)n*K + k0 + kq);
    Ws[kq+0][m_l]=wv.x; Ws[kq+1][m_l]=wv.y; Ws[kq+2][m_l]=wv.z; Ws[kq+3][m_l]=wv.w;
    __syncthreads();

    #pragma unroll
    for (int k = 0; k < 16; k++){
      float4 a = *(const float4*)&As[k][m0];
      float4 b = *(const float4*)&Ws[k][n0];
      acc[0][0]+=a.x*b.x; acc[0][1]+=a.x*b.y; acc[0][2]+=a.x*b.z; acc[0][3]+=a.x*b.w;
      acc[1][0]+=a.y*b.x; acc[1][1]+=a.y*b.y; acc[1][2]+=a.y*b.z; acc[1][3]+=a.y*b.w;
      acc[2][0]+=a.z*b.x; acc[2][1]+=a.z*b.y; acc[2][2]+=a.z*b.z; acc[2][3]+=a.z*b.w;
      acc[3][0]+=a.w*b.x; acc[3][1]+=a.w*b.y; acc[3][2]+=a.w*b.z; acc[3][3]+=a.w*b.w;
    }
    __syncthreads();
  }

  #pragma unroll
  for (int i = 0; i < 4; i++){
    int row = mtile*64 + (tid & 15)*4 + i;
    if (row >= M) continue;
    #pragma unroll
    for (int j = 0; j < 4; j++){
      int col = ntile*64 + (tid >> 4)*4 + j;
      if (col >= N) continue;
      float val = acc[i][j];
      if (MODE == 2) val = softplusf(val + bias[col]);
      if (CF == 0) Cf[(size_t)row*ldc + col] = val;
      else         Cu[(size_t)row*ldc + col] = f2b(val);
    }
  }
}

// ---------------- depthwise causal conv(4) + bias + silu ----------------
__global__ __launch_bounds__(256) void conv_k(const u16* __restrict__ xpre, const float* __restrict__ cw,
                                              const float* __restrict__ cb, u16* __restrict__ xc){
  int idx = blockIdx.x*256 + threadIdx.x;
  int e = idx & (DINNER-1);
  int l = (idx >> 11) % SLEN;
  int b = idx / (SLEN*DINNER);
  float a = cb[e];
  #pragma unroll
  for (int k = 0; k < 4; k++){
    int li = l - 3 + k;
    if (li >= 0) a += cw[e*4 + k] * b2f(xpre[((size_t)(b*SLEN + li))*DINNER + e]);
  }
  xc[((size_t)(b*SLEN + l))*DINNER + e] = f2b(siluf(a));
}

// ---------------- selective scan v2 (whole-seq B/C in LDS, pipelined) ----------------
__global__ __launch_bounds__(256) void scan_k(u16* __restrict__ dy, const u16* __restrict__ xc,
                                              const float* __restrict__ dbc, const float* __restrict__ A_log){
  __shared__ float sB[SLEN*16];
  __shared__ float sC[SLEN*16];
  int b = blockIdx.x >> 3;
  int e = (blockIdx.x & 7)*256 + threadIdx.x;
  int base = b*SLEN;
  for (int i = threadIdx.x; i < SLEN*32; i += 256){
    int l = i >> 5, n = i & 31;
    float v = dbc[(size_t)(base + l)*96 + 64 + n];
    if (n < 16) sB[l*16 + n] = v;
    else        sC[l*16 + (n - 16)] = v;
  }
  float A[16], h[16];
  #pragma unroll
  for (int n = 0; n < 16; n++){ A[n] = -__expf(A_log[(size_t)e*DSTATE + n]); h[n] = 0.f; }
  __syncthreads();

  size_t idx = (size_t)base*DINNER + e;
  float dv = b2f(dy[idx]);
  float xv = b2f(xc[idx]);
  for (int l = 0; l < SLEN; l++){
    size_t nidx = (l+1 < SLEN) ? idx + DINNER : idx;
    float dv_n = b2f(dy[nidx]);
    float xv_n = b2f(xc[nidx]);
    float dx = dv * xv;
    const float* Bl = &sB[l*16];
    const float* Cl = &sC[l*16];
    float y = 0.f;
    #pragma unroll
    for (int n = 0; n < 16; n++){
      h[n] = __expf(dv*A[n])*h[n] + dx*Bl[n];
      y += h[n]*Cl[n];
    }
    dy[idx] = f2b(y);
    idx += DINNER;
    dv = dv_n; xv = xv_n;
  }
}

// ---------------- gate ----------------
__global__ __launch_bounds__(256) void gate_k(u16* __restrict__ y, const u16* __restrict__ xc,
                                              const u16* __restrict__ zb, const float* __restrict__ Dp){
  int idx = blockIdx.x*256 + threadIdx.x;
  int e = idx & (DINNER-1);
  int t = (idx >> 11) % TLEN;
  int b = idx / (TLEN*DINNER);
  int r = b*SLEN + TLEN + t;
  float zv = b2f(zb[((size_t)b*TLEN + t)*DINNER + e]);
  float yv = b2f(y[(size_t)r*DINNER + e]) + b2f(xc[(size_t)r*DINNER + e])*Dp[e];
  y[(size_t)r*DINNER + e] = f2b(yv * siluf(zv));
}

// ---------------- final residual + LN -> f32 out ----------------
__global__ __launch_bounds__(256) void final_k(const u16* __restrict__ seqb, const float* __restrict__ mix,
                                               const float* __restrict__ g, const float* __restrict__ bb,
                                               float* __restrict__ out){
  __shared__ float r1[256], r2[256];
  int ro = blockIdx.x; int b = ro / TLEN;
  int rr = ro + TLEN*(b+1);
  int tid = threadIdx.x;
  float v[4]; float s = 0.f, s2 = 0.f;
  for (int i = 0; i < 4; i++){
    int d = tid + i*256;
    float val = b2f(seqb[(size_t)rr*DMODEL + d]) + mix[(size_t)ro*DMODEL + d];
    v[i] = val; s += val; s2 += val*val;
  }
  r1[tid] = s; r2[tid] = s2; __syncthreads();
  for (int st = 128; st > 0; st >>= 1){
    if (tid < st){ r1[tid]+=r1[tid+st]; r2[tid]+=r2[tid+st]; }
    __syncthreads();
  }
  float mu = r1[0]/1024.f;
  float var = r2[0]/1024.f - mu*mu;
  float rs = rsqrtf(var + 1e-5f);
  for (int i = 0; i < 4; i++){
    int d = tid + i*256;
    out[(size_t)ro*DMODEL + d] = (v[i]-mu)*rs*g[d] + bb[d];
  }
}

extern "C" void kernel_launch(void* const* d_in, const int* in_sizes, int n_in,
                              void* d_out, int out_size, void* d_ws, size_t ws_size,
                              hipStream_t stream){
  const float* x_r       = (const float*)d_in[0];
  const int*   timesteps = (const int*)d_in[1];
  const float* motion    = (const float*)d_in[2];
  const float* time_w1   = (const float*)d_in[3];
  const float* time_b1   = (const float*)d_in[4];
  const float* time_w2   = (const float*)d_in[5];
  const float* time_b2   = (const float*)d_in[6];
  const float* pos_emb   = (const float*)d_in[7];
  const float* ln_g      = (const float*)d_in[8];
  const float* ln_b      = (const float*)d_in[9];
  const float* in_proj_w = (const float*)d_in[10];
  const float* conv_w    = (const float*)d_in[11];
  const float* conv_b    = (const float*)d_in[12];
  const float* x_proj_w  = (const float*)d_in[13];
  const float* dt_proj_w = (const float*)d_in[14];
  const float* dt_proj_b = (const float*)d_in[15];
  const float* A_log     = (const float*)d_in[16];
  const float* Dp        = (const float*)d_in[17];
  const float* out_proj_w= (const float*)d_in[18];
  const float* rms_w     = (const float*)d_in[19];
  float* out = (float*)d_out;

  float* w = (float*)d_ws;
  const size_t o_temb = 0;
  const size_t o_hmid = o_temb + 4096;
  const size_t o_embt = o_hmid + 8192;
  const size_t o_rstd = o_embt + 4096;
  const size_t o_dbc  = o_rstd + 2048;
  const size_t o_mix  = o_dbc  + (size_t)BSZ*SLEN*96;
  const size_t f32_end= o_mix  + (size_t)BSZ*TLEN*DMODEL;
  u16* ub    = (u16*)(w + f32_end);
  u16* seqb  = ub;
  u16* xcpre = seqb  + (size_t)BSZ*SLEN*DMODEL;
  u16* zb    = xcpre + (size_t)BSZ*SLEN*DINNER;
  u16* xc    = zb    + (size_t)BSZ*TLEN*DINNER;
  u16* yb    = xcpre;                               // reuse after conv
  const size_t needed = f32_end*sizeof(float)
                      + (size_t)(1605632 + 3211264 + 1605632 + 3211264)*sizeof(u16);
  if (ws_size < needed){
    zero_out_k<<<(out_size + 255)/256, 256, 0, stream>>>(out, out_size);
    return;
  }

  temb_k<<<8, 256, 0, stream>>>(timesteps, w + o_temb);
  mlp_k<<<2048, 256, 0, stream>>>(w + o_temb, time_w1, time_b1, w + o_hmid, 1024, 2048, 1);
  mlp_k<<<1024, 256, 0, stream>>>(w + o_hmid, time_w2, time_b2, w + o_embt, 2048, 1024, 0);
  build_seq_k<<<BSZ*SLEN, 256, 0, stream>>>(x_r, motion, pos_emb, w + o_embt, ln_g, ln_b,
                                            seqb, w + o_rstd);
  // in_proj via MFMA: (1568,1024)x(4096,1024)^T
  mgemm_k<0><<<dim3(64, 25), 256, 0, stream>>>(seqb, DMODEL, BSZ*SLEN, DMODEL,
                                               in_proj_w, 2*DINNER, nullptr, 0,
                                               w + o_rstd, rms_w, xcpre, zb);
  conv_k<<<(BSZ*SLEN*DINNER)/256, 256, 0, stream>>>(xcpre, conv_w, conv_b, xc);
  gemm_k<1,1,0><<<dim3(2, 25), 256, 0, stream>>>(xc, DINNER, BSZ*SLEN, DINNER,
                                                 x_proj_w, 96, w + o_dbc, 96, nullptr);
  gemm_k<2,0,1><<<dim3(32, 25), 256, 0, stream>>>(w + o_dbc, 96, BSZ*SLEN, DTRANK,
                                                  dt_proj_w, DINNER, yb, DINNER, dt_proj_b);
  scan_k<<<BSZ*8, 256, 0, stream>>>(yb, xc, w + o_dbc, A_log);
  gate_k<<<(BSZ*TLEN*DINNER)/256, 256, 0, stream>>>(yb, xc, zb, Dp);
  // out_proj via MFMA: (784,2048)x(1024,2048)^T, row-remapped A
  mgemm_k<3><<<dim3(16, 13), 256, 0, stream>>>(yb, DINNER, BSZ*TLEN, DINNER,
                                               out_proj_w, DMODEL, w + o_mix, DMODEL,
                                               nullptr, nullptr, nullptr, nullptr);
  final_k<<<BSZ*TLEN, 256, 0, stream>>>(seqb, w + o_mix, ln_g, ln_b, out);
}